// Round 2
// baseline (127.814 us; speedup 1.0000x reference)
//
#include <hip/hip_runtime.h>

#define L_IN   32768
#define L_OUT  32766          // (32768 - 3) + 1
#define C_IN   32
#define C_OUT  32
#define KW     3
#define TILE_L 128            // output positions per tile
#define TPB    4              // tiles per block (pipelined)
#define XROWS  130            // 128 + 2 halo
#define PITCHW 32             // u32 words per transposed row (no pad; XOR swizzle)
#define LDSW   (XROWS * PITCHW)

typedef __attribute__((ext_vector_type(8))) short bf16x8;
typedef __attribute__((ext_vector_type(4))) float f32x4;
typedef __attribute__((ext_vector_type(4))) unsigned int u32x4;

#define PIN(v_) asm volatile("" : "+v"(v_))

// packed hi/lo split: p = [lo16 : hi16]; hi = rne(v), lo = trunc(v - hi)
__device__ __forceinline__ unsigned pack_split(float v) {
    unsigned u = __float_as_uint(v);
    unsigned r = u + 0x7fffu + ((u >> 16) & 1u);          // rne for hi
    float lo = v - __uint_as_float(r & 0xffff0000u);
    return (__float_as_uint(lo) & 0xffff0000u) | (r >> 16);
}

// LDS word index for logical (l, ci): granule XOR swizzle keeps 16B chunks
// aligned while spreading the 8 ci-granules across banks per row.
__device__ __forceinline__ int lds_word(int l, int ci) {
    return l * PITCHW + ((((ci >> 2) ^ (l & 7)) << 2) | (ci & 3));
}

// ---- prekernel: pack w into per-lane MFMA A-fragments, bf16 hi/lo split.
// A[m=lane&15][k=(lane>>4)*8+j] = w[co=cot*16+m][ci=k][kw],  f = kw*2+cot
__global__ void prep_w(const float* __restrict__ w, unsigned short* __restrict__ wtf) {
    const int i = blockIdx.x * 256 + threadIdx.x;     // 0..3071
    if (i >= 6 * 64 * 8) return;
    const int f    = i >> 9;
    const int rr   = i & 511;
    const int lane = rr >> 3;
    const int j    = rr & 7;
    const int kw   = f >> 1;
    const int cot  = f & 1;
    const int co   = cot * 16 + (lane & 15);
    const int ci   = (lane >> 4) * 8 + j;
    const float v  = w[(co * C_IN + ci) * KW + kw];
    unsigned u = __float_as_uint(v);
    unsigned r = u + 0x7fffu + ((u >> 16) & 1u);
    unsigned short hi = (unsigned short)(r >> 16);
    float lof = v - __uint_as_float(r & 0xffff0000u);
    unsigned lu = __float_as_uint(lof);
    unsigned lr = lu + 0x7fffu + ((lu >> 16) & 1u);
    unsigned short lo = (unsigned short)(lr >> 16);
    wtf[(f * 64 + lane) * 16 + j]     = hi;
    wtf[(f * 64 + lane) * 16 + 8 + j] = lo;
}

__global__ __launch_bounds__(256, 4) void conv1d_mfma(
    const float* __restrict__ x, const unsigned short* __restrict__ wtf,
    float* __restrict__ out)
{
    __shared__ __attribute__((aligned(16))) unsigned xp[2][LDSW];   // 2 x 16.6 KB

    const int tid  = threadIdx.x;
    const int lane = tid & 63;
    const int wv   = tid >> 6;                 // wave 0..3
    const int bb   = blockIdx.x >> 6;          // batch 0..15
    const int grp  = blockIdx.x & 63;          // tile group 0..63
    const int lg0  = grp * (TILE_L * TPB);     // 512 cols per block

    const float* xb = x + (size_t)bb * C_IN * L_IN;

    // ---- weight fragments: load once, pinned below so they stay in VGPRs
    u32x4 wah[6], wal[6];
#pragma unroll
    for (int f = 0; f < 6; ++f) {
        const u32x4* p = (const u32x4*)(wtf + (f * 64 + lane) * 16);
        wah[f] = p[0];
        wal[f] = p[1];
    }

    const int c   = tid & 31;                  // l within 32-chunk
    const int rr0 = tid >> 5;                  // ci base 0..7
    const int n   = lane & 15;                 // MFMA col (l offset)
    const int kg  = lane >> 4;                 // k-group (ci block of 8)
    const int lb  = wv * 32;                   // wave's l window

    float sv[4][4];                            // staged tile (regs)
    float hv;                                  // halo element (tid<64)

    auto LOADT = [&](int l0) {
#pragma unroll
        for (int r = 0; r < 4; ++r) {
            const float* src = xb + (size_t)(rr0 + r * 8) * L_IN + l0;
#pragma unroll
            for (int q = 0; q < 4; ++q)
                sv[r][q] = src[c + q * 32];
        }
        hv = 0.f;
        if (tid < 64) {
            const int gl = l0 + TILE_L + (tid & 1);
            if (gl < L_IN) hv = xb[(size_t)(tid >> 1) * L_IN + gl];
        }
        asm volatile("" ::: "memory");         // keep load issue above the barrier
    };
    auto WRITET = [&](int buf) {
        unsigned* xs = xp[buf];
#pragma unroll
        for (int r = 0; r < 4; ++r)
#pragma unroll
            for (int q = 0; q < 4; ++q)
                xs[lds_word(c + q * 32, rr0 + r * 8)] = pack_split(sv[r][q]);
        if (tid < 64)
            xs[lds_word(TILE_L + (tid & 1), tid >> 1)] = pack_split(hv);
    };

    // ---- prologue: stage tile 0 (w-load latency hides under it), then pin w
    LOADT(lg0);
    WRITET(0);
#pragma unroll
    for (int f = 0; f < 6; ++f) { PIN(wah[f]); PIN(wal[f]); }

    float* ob = out + (size_t)bb * C_OUT * L_OUT;

#pragma unroll
    for (int t = 0; t < TPB; ++t) {
        const int l0 = lg0 + t * TILE_L;
        if (t + 1 < TPB) LOADT(l0 + TILE_L);   // issue next tile's loads early
        __syncthreads();                        // buf[t&1] ready

        const unsigned* xs = xp[t & 1];
        f32x4 acc[2][2];
#pragma unroll
        for (int a = 0; a < 2; ++a)
#pragma unroll
            for (int bq = 0; bq < 2; ++bq)
                acc[a][bq] = (f32x4){0.f, 0.f, 0.f, 0.f};

#pragma unroll
        for (int kw = 0; kw < KW; ++kw) {
#pragma unroll
            for (int lt = 0; lt < 2; ++lt) {
                const int lrow = lb + lt * 16 + n + kw;          // <= 129
                const int base = lrow * PITCHW;
                const int sw   = lrow & 7;
                const u32x4 pa = *(const u32x4*)&xs[base + (((kg * 2 + 0) ^ sw) << 2)];
                const u32x4 pb = *(const u32x4*)&xs[base + (((kg * 2 + 1) ^ sw) << 2)];
                u32x4 BH, BL;
                BH[0] = (pa[0] & 0xffffu) | (pa[1] << 16);
                BH[1] = (pa[2] & 0xffffu) | (pa[3] << 16);
                BH[2] = (pb[0] & 0xffffu) | (pb[1] << 16);
                BH[3] = (pb[2] & 0xffffu) | (pb[3] << 16);
                BL[0] = (pa[0] >> 16) | (pa[1] & 0xffff0000u);
                BL[1] = (pa[2] >> 16) | (pa[3] & 0xffff0000u);
                BL[2] = (pb[0] >> 16) | (pb[1] & 0xffff0000u);
                BL[3] = (pb[2] >> 16) | (pb[3] & 0xffff0000u);
                const bf16x8 bh = __builtin_bit_cast(bf16x8, BH);
                const bf16x8 bl = __builtin_bit_cast(bf16x8, BL);
#pragma unroll
                for (int cot = 0; cot < 2; ++cot) {
                    const int f = kw * 2 + cot;
                    const bf16x8 ah = __builtin_bit_cast(bf16x8, wah[f]);
                    const bf16x8 al = __builtin_bit_cast(bf16x8, wal[f]);
                    acc[cot][lt] = __builtin_amdgcn_mfma_f32_16x16x32_bf16(ah, bh, acc[cot][lt], 0, 0, 0);
                    acc[cot][lt] = __builtin_amdgcn_mfma_f32_16x16x32_bf16(ah, bl, acc[cot][lt], 0, 0, 0);
                    acc[cot][lt] = __builtin_amdgcn_mfma_f32_16x16x32_bf16(al, bh, acc[cot][lt], 0, 0, 0);
                }
            }
        }

        if (t + 1 < TPB) WRITET((t + 1) & 1);  // convert+write after compute (vmcnt wait here)

        // ---- store: D layout col=lane&15 (l), row=(lane>>4)*4+r (co)
        const int lw = l0 + lb;
        if (lw + 31 < L_OUT) {                  // fast path (all tiles but the last)
#pragma unroll
            for (int cot = 0; cot < 2; ++cot)
#pragma unroll
                for (int lt = 0; lt < 2; ++lt) {
                    float* op = ob + (size_t)(cot * 16 + kg * 4) * L_OUT + lw + lt * 16 + n;
#pragma unroll
                    for (int r = 0; r < 4; ++r)
                        op[(size_t)r * L_OUT] = acc[cot][lt][r];
                }
        } else {
#pragma unroll
            for (int cot = 0; cot < 2; ++cot)
#pragma unroll
                for (int lt = 0; lt < 2; ++lt) {
                    const int l = lw + lt * 16 + n;
                    if (l < L_OUT) {
                        float* op = ob + (size_t)(cot * 16 + kg * 4) * L_OUT + l;
#pragma unroll
                        for (int r = 0; r < 4; ++r)
                            op[(size_t)r * L_OUT] = acc[cot][lt][r];
                    }
                }
        }
    }
}

extern "C" void kernel_launch(void* const* d_in, const int* in_sizes, int n_in,
                              void* d_out, int out_size, void* d_ws, size_t ws_size,
                              hipStream_t stream) {
    const float* x = (const float*)d_in[0];
    const float* w = (const float*)d_in[1];
    float* out     = (float*)d_out;
    unsigned short* wtf = (unsigned short*)d_ws;   // 6144 ushorts = 12 KB scratch

    prep_w<<<dim3(12), 256, 0, stream>>>(w, wtf);
    conv1d_mfma<<<dim3(16 * 64), 256, 0, stream>>>(x, wtf, out);
}

// Round 5
// 119.784 us; speedup vs baseline: 1.0670x; 1.0670x over previous
//
#include <hip/hip_runtime.h>

#define L_IN   32768
#define L_OUT  32766          // (32768 - 3) + 1
#define C_IN   32
#define C_OUT  32
#define KW     3
#define TILE_L 128            // output positions per tile
#define TPB    2              // tiles per block
#define NGRP   128            // 32768 / (TILE_L*TPB)
#define XROWS  130            // 128 + 2 halo
#define PITCHW 32             // u32 words per transposed row (XOR swizzle, no pad)
#define LDSW   (XROWS * PITCHW)   // 4160 u32 = 16.6 KB
#define WPLANE 3072           // ushorts per weight plane (hi | lo)

typedef __attribute__((ext_vector_type(8))) short bf16x8;
typedef __attribute__((ext_vector_type(4))) float f32x4;
typedef __attribute__((ext_vector_type(4))) unsigned int u32x4;

// packed hi/lo split: p = [lo16 : hi16]; hi = rne(v), lo = v - hi
__device__ __forceinline__ unsigned pack_split(float v) {
    unsigned u = __float_as_uint(v);
    unsigned r = u + 0x7fffu + ((u >> 16) & 1u);          // rne for hi
    float lo = v - __uint_as_float(r & 0xffff0000u);
    return (__float_as_uint(lo) & 0xffff0000u) | (r >> 16);
}

// LDS word index for logical (l, ci): granule XOR swizzle keeps 16B chunks
// aligned while spreading the 8 ci-granules across banks per row.
__device__ __forceinline__ int lds_word(int l, int ci) {
    return l * PITCHW + ((((ci >> 2) ^ (l & 7)) << 2) | (ci & 3));
}

// ---- prekernel: pack w into per-lane MFMA A-fragments, bf16 hi/lo in two
// SEPARATE planes so per-lane fragment reads are canonical stride-16B.
// hi at wtf[(f*64+lane)*8+j], lo at wtf[3072 + (f*64+lane)*8+j],
// A[m=lane&15][k=(lane>>4)*8+j] = w[co=cot*16+m][ci=k][kw],  f = kw*2+cot
__global__ void prep_w(const float* __restrict__ w, unsigned short* __restrict__ wtf) {
    const int i = blockIdx.x * 256 + threadIdx.x;     // 0..3071
    if (i >= 6 * 64 * 8) return;
    const int f    = i >> 9;
    const int rr   = i & 511;
    const int lane = rr >> 3;
    const int j    = rr & 7;
    const int kw   = f >> 1;
    const int cot  = f & 1;
    const int co   = cot * 16 + (lane & 15);
    const int ci   = (lane >> 4) * 8 + j;
    const float v  = w[(co * C_IN + ci) * KW + kw];
    unsigned u = __float_as_uint(v);
    unsigned r = u + 0x7fffu + ((u >> 16) & 1u);
    unsigned short hi = (unsigned short)(r >> 16);
    float lof = v - __uint_as_float(r & 0xffff0000u);
    unsigned lu = __float_as_uint(lof);
    unsigned lr = lu + 0x7fffu + ((lu >> 16) & 1u);
    unsigned short lo = (unsigned short)(lr >> 16);
    wtf[(f * 64 + lane) * 8 + j]          = hi;
    wtf[WPLANE + (f * 64 + lane) * 8 + j] = lo;
}

__global__ __launch_bounds__(256, 4) void conv1d_mfma(
    const float* __restrict__ x, const unsigned short* __restrict__ wtf,
    float* __restrict__ out)
{
    __shared__ __attribute__((aligned(16))) unsigned       xs[LDSW];        // 16.6 KB
    __shared__ __attribute__((aligned(16))) unsigned short wl[2 * WPLANE];  // 12.3 KB

    const int tid  = threadIdx.x;
    const int lane = tid & 63;
    const int wv   = tid >> 6;                 // wave 0..3
    const int bb   = blockIdx.x >> 7;          // batch 0..15
    const int grp  = blockIdx.x & (NGRP - 1);  // 0..127
    const int lg0  = grp * (TILE_L * TPB);     // 256 cols per block

    const float* xb = x + (size_t)bb * C_IN * L_IN;

    // ---- weights -> LDS (once per block; L2-hot source). Linear copy.
    {
        const u32x4* wsv = (const u32x4*)wtf;
        u32x4*       wdv = (u32x4*)wl;
#pragma unroll
        for (int i = 0; i < 3; ++i)
            wdv[tid * 3 + i] = wsv[tid * 3 + i];
    }

    const int c   = tid & 31;                  // l within 32-chunk
    const int rr0 = tid >> 5;                  // ci base 0..7
    const int n   = lane & 15;                 // MFMA col (l offset)
    const int kg  = lane >> 4;                 // k-group (ci block of 8)
    const int lb  = wv * 32;                   // wave's l window

    float sv[4][4];                            // staged x tile (regs)
    float hv;                                  // halo element (tid<64)

    auto LOADT = [&](int l0) {
#pragma unroll
        for (int r = 0; r < 4; ++r) {
            const float* src = xb + (size_t)(rr0 + r * 8) * L_IN + l0;
#pragma unroll
            for (int q = 0; q < 4; ++q)
                sv[r][q] = src[c + q * 32];
        }
        hv = 0.f;
        if (tid < 64) {
            const int gl = l0 + TILE_L + (tid & 1);
            if (gl < L_IN) hv = xb[(size_t)(tid >> 1) * L_IN + gl];
        }
        asm volatile("" ::: "memory");         // pin the issue point
    };
    auto WRITET = [&]() {
#pragma unroll
        for (int r = 0; r < 4; ++r)
#pragma unroll
            for (int q = 0; q < 4; ++q)
                xs[lds_word(c + q * 32, rr0 + r * 8)] = pack_split(sv[r][q]);
        if (tid < 64)
            xs[lds_word(TILE_L + (tid & 1), tid >> 1)] = pack_split(hv);
    };

    LOADT(lg0);                                // tile 0 x-loads in flight

    float* ob = out + (size_t)bb * C_OUT * L_OUT;

#pragma unroll
    for (int t = 0; t < TPB; ++t) {
        const int l0 = lg0 + t * TILE_L;
        WRITET();                              // writes THIS tile (sv = tile t); counted wait
        if (t + 1 < TPB) LOADT(l0 + TILE_L);   // THEN clobber sv with next tile (in flight
                                               // across the whole MFMA phase below)
        __syncthreads();                       // xs (and wl at t=0) visible

        f32x4 acc[2][2];
#pragma unroll
        for (int a = 0; a < 2; ++a)
#pragma unroll
            for (int bq = 0; bq < 2; ++bq)
                acc[a][bq] = (f32x4){0.f, 0.f, 0.f, 0.f};

#pragma unroll
        for (int kw = 0; kw < KW; ++kw) {
            // weight fragments for this kw: 4 x ds_read_b128, canonical layout
            const int f0 = kw * 2, f1 = kw * 2 + 1;
            const bf16x8 ah0 = *(const bf16x8*)&wl[(f0 * 64 + lane) * 8];
            const bf16x8 al0 = *(const bf16x8*)&wl[WPLANE + (f0 * 64 + lane) * 8];
            const bf16x8 ah1 = *(const bf16x8*)&wl[(f1 * 64 + lane) * 8];
            const bf16x8 al1 = *(const bf16x8*)&wl[WPLANE + (f1 * 64 + lane) * 8];
#pragma unroll
            for (int lt = 0; lt < 2; ++lt) {
                const int lrow = lb + lt * 16 + n + kw;          // <= 129
                const int base = lrow * PITCHW;
                const int sw   = lrow & 7;
                const u32x4 pa = *(const u32x4*)&xs[base + (((kg * 2 + 0) ^ sw) << 2)];
                const u32x4 pb = *(const u32x4*)&xs[base + (((kg * 2 + 1) ^ sw) << 2)];
                u32x4 BH, BL;
                BH[0] = (pa[0] & 0xffffu) | (pa[1] << 16);
                BH[1] = (pa[2] & 0xffffu) | (pa[3] << 16);
                BH[2] = (pb[0] & 0xffffu) | (pb[1] << 16);
                BH[3] = (pb[2] & 0xffffu) | (pb[3] << 16);
                BL[0] = (pa[0] >> 16) | (pa[1] & 0xffff0000u);
                BL[1] = (pa[2] >> 16) | (pa[3] & 0xffff0000u);
                BL[2] = (pb[0] >> 16) | (pb[1] & 0xffff0000u);
                BL[3] = (pb[2] >> 16) | (pb[3] & 0xffff0000u);
                const bf16x8 bh = __builtin_bit_cast(bf16x8, BH);
                const bf16x8 bl = __builtin_bit_cast(bf16x8, BL);

                acc[0][lt] = __builtin_amdgcn_mfma_f32_16x16x32_bf16(ah0, bh, acc[0][lt], 0, 0, 0);
                acc[0][lt] = __builtin_amdgcn_mfma_f32_16x16x32_bf16(ah0, bl, acc[0][lt], 0, 0, 0);
                acc[0][lt] = __builtin_amdgcn_mfma_f32_16x16x32_bf16(al0, bh, acc[0][lt], 0, 0, 0);
                acc[1][lt] = __builtin_amdgcn_mfma_f32_16x16x32_bf16(ah1, bh, acc[1][lt], 0, 0, 0);
                acc[1][lt] = __builtin_amdgcn_mfma_f32_16x16x32_bf16(ah1, bl, acc[1][lt], 0, 0, 0);
                acc[1][lt] = __builtin_amdgcn_mfma_f32_16x16x32_bf16(al1, bh, acc[1][lt], 0, 0, 0);
            }
        }

        // ---- store (stores are never vmcnt-waited in the loop)
        const int lw = l0 + lb;
        if (lw + 31 < L_OUT) {                  // fast path
#pragma unroll
            for (int cot = 0; cot < 2; ++cot)
#pragma unroll
                for (int lt = 0; lt < 2; ++lt) {
                    float* op = ob + (size_t)(cot * 16 + kg * 4) * L_OUT + lw + lt * 16 + n;
#pragma unroll
                    for (int r = 0; r < 4; ++r)
                        op[(size_t)r * L_OUT] = acc[cot][lt][r];
                }
        } else {
#pragma unroll
            for (int cot = 0; cot < 2; ++cot)
#pragma unroll
                for (int lt = 0; lt < 2; ++lt) {
                    const int l = lw + lt * 16 + n;
                    if (l < L_OUT) {
                        float* op = ob + (size_t)(cot * 16 + kg * 4) * L_OUT + l;
#pragma unroll
                        for (int r = 0; r < 4; ++r)
                            op[(size_t)r * L_OUT] = acc[cot][lt][r];
                    }
                }
        }

        if (t + 1 < TPB) __syncthreads();      // all xs reads done before next WRITET
    }
}

extern "C" void kernel_launch(void* const* d_in, const int* in_sizes, int n_in,
                              void* d_out, int out_size, void* d_ws, size_t ws_size,
                              hipStream_t stream) {
    const float* x = (const float*)d_in[0];
    const float* w = (const float*)d_in[1];
    float* out     = (float*)d_out;
    unsigned short* wtf = (unsigned short*)d_ws;   // 6144 ushorts = 12 KB scratch

    prep_w<<<dim3(12), 256, 0, stream>>>(w, wtf);
    conv1d_mfma<<<dim3(16 * NGRP), 256, 0, stream>>>(x, wtf, out);
}

// Round 6
// 119.143 us; speedup vs baseline: 1.0728x; 1.0054x over previous
//
#include <hip/hip_runtime.h>

#define L_IN   32768
#define L_OUT  32766          // (32768 - 3) + 1
#define C_IN   32
#define C_OUT  32
#define KW     3
#define TILE_L 128            // output positions per tile
#define TPB    4              // tiles per block (2-deep prefetch pipeline)
#define NGRP   64             // 32768 / (TILE_L*TPB)
#define XROWS  130            // 128 + 2 halo
#define PITCHW 32             // u32 words per transposed row (XOR swizzle, no pad)
#define LDSW   (XROWS * PITCHW)   // 4160 u32 = 16.6 KB
#define WPLANE 3072           // ushorts per weight plane (hi | lo)

typedef __attribute__((ext_vector_type(8))) short bf16x8;
typedef __attribute__((ext_vector_type(4))) float f32x4;
typedef __attribute__((ext_vector_type(4))) unsigned int u32x4;

// packed hi/lo split: p = [lo16 : hi16]; hi = rne(v), lo = v - hi
__device__ __forceinline__ unsigned pack_split(float v) {
    unsigned u = __float_as_uint(v);
    unsigned r = u + 0x7fffu + ((u >> 16) & 1u);          // rne for hi
    float lo = v - __uint_as_float(r & 0xffff0000u);
    return (__float_as_uint(lo) & 0xffff0000u) | (r >> 16);
}

// LDS word index for logical (l, ci): granule XOR swizzle keeps 16B chunks
// aligned while spreading the 8 ci-granules across banks per row.
__device__ __forceinline__ int lds_word(int l, int ci) {
    return l * PITCHW + ((((ci >> 2) ^ (l & 7)) << 2) | (ci & 3));
}

// ---- prekernel: pack w into per-lane MFMA A-fragments, bf16 hi/lo in two
// SEPARATE planes so per-lane fragment reads are canonical stride-16B.
// hi at wtf[(f*64+lane)*8+j], lo at wtf[3072 + (f*64+lane)*8+j],
// A[m=lane&15][k=(lane>>4)*8+j] = w[co=cot*16+m][ci=k][kw],  f = kw*2+cot
__global__ void prep_w(const float* __restrict__ w, unsigned short* __restrict__ wtf) {
    const int i = blockIdx.x * 256 + threadIdx.x;     // 0..3071
    if (i >= 6 * 64 * 8) return;
    const int f    = i >> 9;
    const int rr   = i & 511;
    const int lane = rr >> 3;
    const int j    = rr & 7;
    const int kw   = f >> 1;
    const int cot  = f & 1;
    const int co   = cot * 16 + (lane & 15);
    const int ci   = (lane >> 4) * 8 + j;
    const float v  = w[(co * C_IN + ci) * KW + kw];
    unsigned u = __float_as_uint(v);
    unsigned r = u + 0x7fffu + ((u >> 16) & 1u);
    unsigned short hi = (unsigned short)(r >> 16);
    float lof = v - __uint_as_float(r & 0xffff0000u);
    unsigned lu = __float_as_uint(lof);
    unsigned lr = lu + 0x7fffu + ((lu >> 16) & 1u);
    unsigned short lo = (unsigned short)(lr >> 16);
    wtf[(f * 64 + lane) * 8 + j]          = hi;
    wtf[WPLANE + (f * 64 + lane) * 8 + j] = lo;
}

__global__ __launch_bounds__(256, 4) void conv1d_mfma(
    const float* __restrict__ x, const unsigned short* __restrict__ wtf,
    float* __restrict__ out)
{
    __shared__ __attribute__((aligned(16))) unsigned       xs[LDSW];        // 16.6 KB
    __shared__ __attribute__((aligned(16))) unsigned short wl[2 * WPLANE];  // 12.3 KB

    const int tid  = threadIdx.x;
    const int lane = tid & 63;
    const int wv   = tid >> 6;                 // wave 0..3
    const int bb   = blockIdx.x >> 6;          // batch 0..15
    const int grp  = blockIdx.x & (NGRP - 1);  // 0..63
    const int lg0  = grp * (TILE_L * TPB);     // 512 cols per block

    const float* xb = x + (size_t)bb * C_IN * L_IN;

    // ---- weights -> LDS (once per block; L2-hot source). Linear copy.
    {
        const u32x4* wsv = (const u32x4*)wtf;
        u32x4*       wdv = (u32x4*)wl;
#pragma unroll
        for (int i = 0; i < 3; ++i)
            wdv[tid * 3 + i] = wsv[tid * 3 + i];
    }

    const int c   = tid & 31;                  // l within 32-chunk
    const int rr0 = tid >> 5;                  // ci base 0..7
    const int n   = lane & 15;                 // MFMA col (l offset)
    const int kg  = lane >> 4;                 // k-group (ci block of 8)
    const int lb  = wv * 32;                   // wave's l window

    float sv[2][4][4];                         // staged x tiles (2-deep prefetch)
    float hv[2];                               // halo elements (tid<64)

    auto LOADT = [&](int l0, int s) {
#pragma unroll
        for (int r = 0; r < 4; ++r) {
            const float* src = xb + (size_t)(rr0 + r * 8) * L_IN + l0;
#pragma unroll
            for (int q = 0; q < 4; ++q)
                sv[s][r][q] = src[c + q * 32];
        }
        hv[s] = 0.f;
        if (tid < 64) {
            const int gl = l0 + TILE_L + (tid & 1);
            if (gl < L_IN) hv[s] = xb[(size_t)(tid >> 1) * L_IN + gl];
        }
        asm volatile("" ::: "memory");         // pin the issue point
    };
    auto WRITET = [&](int s) {
#pragma unroll
        for (int r = 0; r < 4; ++r)
#pragma unroll
            for (int q = 0; q < 4; ++q)
                xs[lds_word(c + q * 32, rr0 + r * 8)] = pack_split(sv[s][r][q]);
        if (tid < 64)
            xs[lds_word(TILE_L + (tid & 1), tid >> 1)] = pack_split(hv[s]);
    };

    LOADT(lg0, 0);                             // tiles 0 and 1 in flight
    LOADT(lg0 + TILE_L, 1);

    float* ob = out + (size_t)bb * C_OUT * L_OUT;

#pragma unroll
    for (int t = 0; t < TPB; ++t) {
        const int l0 = lg0 + t * TILE_L;
        WRITET(t & 1);                         // tile t: loads issued 2 phases ago
        if (t + 2 < TPB) LOADT(l0 + 2 * TILE_L, t & 1);   // refill freed buffer
        __syncthreads();                       // xs (and wl at t=0) visible

        f32x4 acc[2][2];
#pragma unroll
        for (int a = 0; a < 2; ++a)
#pragma unroll
            for (int bq = 0; bq < 2; ++bq)
                acc[a][bq] = (f32x4){0.f, 0.f, 0.f, 0.f};

#pragma unroll
        for (int kw = 0; kw < KW; ++kw) {
            // weight fragments for this kw: 4 x ds_read_b128, canonical layout
            const int f0 = kw * 2, f1 = kw * 2 + 1;
            const bf16x8 ah0 = *(const bf16x8*)&wl[(f0 * 64 + lane) * 8];
            const bf16x8 al0 = *(const bf16x8*)&wl[WPLANE + (f0 * 64 + lane) * 8];
            const bf16x8 ah1 = *(const bf16x8*)&wl[(f1 * 64 + lane) * 8];
            const bf16x8 al1 = *(const bf16x8*)&wl[WPLANE + (f1 * 64 + lane) * 8];
#pragma unroll
            for (int lt = 0; lt < 2; ++lt) {
                const int lrow = lb + lt * 16 + n + kw;          // <= 129
                const int base = lrow * PITCHW;
                const int sw   = lrow & 7;
                const u32x4 pa = *(const u32x4*)&xs[base + (((kg * 2 + 0) ^ sw) << 2)];
                const u32x4 pb = *(const u32x4*)&xs[base + (((kg * 2 + 1) ^ sw) << 2)];
                u32x4 BH, BL;
                BH[0] = (pa[0] & 0xffffu) | (pa[1] << 16);
                BH[1] = (pa[2] & 0xffffu) | (pa[3] << 16);
                BH[2] = (pb[0] & 0xffffu) | (pb[1] << 16);
                BH[3] = (pb[2] & 0xffffu) | (pb[3] << 16);
                BL[0] = (pa[0] >> 16) | (pa[1] & 0xffff0000u);
                BL[1] = (pa[2] >> 16) | (pa[3] & 0xffff0000u);
                BL[2] = (pb[0] >> 16) | (pb[1] & 0xffff0000u);
                BL[3] = (pb[2] >> 16) | (pb[3] & 0xffff0000u);
                const bf16x8 bh = __builtin_bit_cast(bf16x8, BH);
                const bf16x8 bl = __builtin_bit_cast(bf16x8, BL);

                acc[0][lt] = __builtin_amdgcn_mfma_f32_16x16x32_bf16(ah0, bh, acc[0][lt], 0, 0, 0);
                acc[0][lt] = __builtin_amdgcn_mfma_f32_16x16x32_bf16(ah0, bl, acc[0][lt], 0, 0, 0);
                acc[0][lt] = __builtin_amdgcn_mfma_f32_16x16x32_bf16(al0, bh, acc[0][lt], 0, 0, 0);
                acc[1][lt] = __builtin_amdgcn_mfma_f32_16x16x32_bf16(ah1, bh, acc[1][lt], 0, 0, 0);
                acc[1][lt] = __builtin_amdgcn_mfma_f32_16x16x32_bf16(ah1, bl, acc[1][lt], 0, 0, 0);
                acc[1][lt] = __builtin_amdgcn_mfma_f32_16x16x32_bf16(al1, bh, acc[1][lt], 0, 0, 0);
            }
        }

        // ---- store (stores are never vmcnt-waited in the loop)
        const int lw = l0 + lb;
        if (lw + 31 < L_OUT) {                  // fast path
#pragma unroll
            for (int cot = 0; cot < 2; ++cot)
#pragma unroll
                for (int lt = 0; lt < 2; ++lt) {
                    float* op = ob + (size_t)(cot * 16 + kg * 4) * L_OUT + lw + lt * 16 + n;
#pragma unroll
                    for (int r = 0; r < 4; ++r)
                        op[(size_t)r * L_OUT] = acc[cot][lt][r];
                }
        } else {
#pragma unroll
            for (int cot = 0; cot < 2; ++cot)
#pragma unroll
                for (int lt = 0; lt < 2; ++lt) {
                    const int l = lw + lt * 16 + n;
                    if (l < L_OUT) {
                        float* op = ob + (size_t)(cot * 16 + kg * 4) * L_OUT + l;
#pragma unroll
                        for (int r = 0; r < 4; ++r)
                            op[(size_t)r * L_OUT] = acc[cot][lt][r];
                    }
                }
        }

        if (t + 1 < TPB) __syncthreads();      // all xs reads done before next WRITET
    }
}

extern "C" void kernel_launch(void* const* d_in, const int* in_sizes, int n_in,
                              void* d_out, int out_size, void* d_ws, size_t ws_size,
                              hipStream_t stream) {
    const float* x = (const float*)d_in[0];
    const float* w = (const float*)d_in[1];
    float* out     = (float*)d_out;
    unsigned short* wtf = (unsigned short*)d_ws;   // 6144 ushorts = 12 KB scratch

    prep_w<<<dim3(12), 256, 0, stream>>>(w, wtf);
    conv1d_mfma<<<dim3(16 * NGRP), 256, 0, stream>>>(x, wtf, out);
}